// Round 22
// baseline (103.999 us; speedup 1.0000x reference)
//
#include <hip/hip_runtime.h>

typedef __attribute__((ext_vector_type(4))) float f32x4;
typedef __attribute__((ext_vector_type(16))) float f32x16;
typedef __attribute__((ext_vector_type(4))) unsigned short u16x4;
typedef __attribute__((ext_vector_type(8))) unsigned short u16x8;
typedef __attribute__((ext_vector_type(4))) unsigned int u32x4;
typedef __attribute__((ext_vector_type(8))) __bf16 bf16x8;

#define SZX_E ((size_t)4 * 2048 * 512)  // elements per activation tensor
#define SZW_E ((size_t)512 * 512)

__device__ __forceinline__ unsigned short f2bf(float f) {
  unsigned int u = __builtin_bit_cast(unsigned int, f);
  u += 0x7fffu + ((u >> 16) & 1u);
  return (unsigned short)(u >> 16);
}

__device__ __forceinline__ bf16x8 ld_bf8(const unsigned short* p) {
  return __builtin_bit_cast(bf16x8, *(const u16x8*)p);
}

__device__ __forceinline__ f32x4 mfma16(bf16x8 a, bf16x8 b, f32x4 c) {
  return __builtin_amdgcn_mfma_f32_16x16x32_bf16(a, b, c, 0, 0, 0);
}

__device__ __forceinline__ f32x16 mfma32(bf16x8 a, bf16x8 b, f32x16 c) {
  return __builtin_amdgcn_mfma_f32_32x32x16_bf16(a, b, c, 0, 0, 0);
}

__device__ __forceinline__ unsigned int cvt_pk_bf16(float lo, float hi) {
  unsigned int r;
  asm("v_cvt_pk_bf16_f32 %0, %1, %2" : "=v"(r) : "v"(lo), "v"(hi));
  return r;
}

__device__ __forceinline__ void plane32_swap(unsigned int& a, unsigned int& b) {
  asm("v_permlane32_swap_b32 %0, %1" : "+v"(a), "+v"(b));
}

// raw v_exp_f32 (2^x); args bounded (|scores*log2e| < ~10) -> equals exp2f.
__device__ __forceinline__ float exp2_fast(float x) {
  float r;
  asm("v_exp_f32 %0, %1" : "=v"(r) : "v"(x));
  return r;
}

// async global->LDS, 16B per lane; LDS dest = WAVE-UNIFORM base, HW adds lane*16
__device__ __forceinline__ void gload16(const void* g, void* l) {
  __builtin_amdgcn_global_load_lds(
      (const __attribute__((address_space(1))) unsigned int*)g,
      (__attribute__((address_space(3))) unsigned int*)l, 16, 0, 0);
}

// counted-vmcnt barrier (T4); sched_barrier fences prevent hoisting (rule #18).
#define VBAR2 do { \
    asm volatile("s_waitcnt vmcnt(2)" ::: "memory"); \
    __builtin_amdgcn_sched_barrier(0); \
    __builtin_amdgcn_s_barrier(); \
    __builtin_amdgcn_sched_barrier(0); \
  } while (0)
#define VBAR0 do { \
    asm volatile("s_waitcnt vmcnt(0)" ::: "memory"); \
    __builtin_amdgcn_sched_barrier(0); \
    __builtin_amdgcn_s_barrier(); \
    __builtin_amdgcn_sched_barrier(0); \
  } while (0)

// ---------------- fused fp32 -> bf16 convert (all 7 tensors, one launch) ----------------
__global__ __launch_bounds__(256) void cvt_all(const float* __restrict__ q_,
                                               const float* __restrict__ k_,
                                               const float* __restrict__ v_,
                                               const float* __restrict__ wq_,
                                               const float* __restrict__ wk_,
                                               const float* __restrict__ wv_,
                                               const float* __restrict__ wo_,
                                               unsigned short* __restrict__ out) {
  const int bq = blockIdx.x;
  const float* src;
  size_t segbase, li;
  if (bq < 12288) {
    const int s = bq >> 12;
    src = (s == 0) ? q_ : (s == 1) ? k_ : v_;
    li = (size_t)(bq & 4095) * 256 + threadIdx.x;
    segbase = (size_t)s * 4194304;
  } else {
    const int s = (bq - 12288) >> 8;
    src = (s == 0) ? wq_ : (s == 1) ? wk_ : (s == 2) ? wv_ : wo_;
    li = (size_t)((bq - 12288) & 255) * 256 + threadIdx.x;
    segbase = 12582912 + (size_t)s * 262144;
  }
  const f32x4 v = *(const f32x4*)(src + li * 4);
  u16x4 r;
  r[0] = f2bf(v[0]); r[1] = f2bf(v[1]); r[2] = f2bf(v[2]); r[3] = f2bf(v[3]);
  *(u16x4*)(out + segbase + li * 4) = r;
}

// ---------------- fused QKV GEMM: z = 0/1/2 -> Q/K/V projection + XCD swizzle ----------------
__global__ __launch_bounds__(256) void gemm_qkv(const unsigned short* __restrict__ base,
                                                const float* __restrict__ bq,
                                                const float* __restrict__ bk,
                                                const float* __restrict__ bv,
                                                unsigned short* __restrict__ outb) {
  __shared__ unsigned short Asb[2][4096];
  __shared__ unsigned short Bsb[2][4096];
  const int z = blockIdx.z;
  const unsigned short* A = base + (size_t)z * SZX_E;
  const unsigned short* Bw = base + 3 * SZX_E + (size_t)z * SZW_E;
  const float* bias = (z == 0) ? bq : (z == 1) ? bk : bv;

  const int tid = threadIdx.x;
  const int l = tid & 63;
  const int w = tid >> 6;
  const int g = l >> 4;
  const int lr = l & 15;
  const int bid = blockIdx.x + (blockIdx.y << 2);
  const int lgg = (bid & 7) * 32 + (bid >> 3);
  const int nB = (lgg & 3) * 128;
  const int mB = (lgg >> 2) * 128;
  const int m0 = (w >> 1) * 64;
  const int n0 = (w & 1) * 64;
  const int ubase = tid & ~63;

  auto stage = [&](int bufi, int kk) {
#pragma unroll
    for (int i = 0; i < 2; i++) {
      const int idx = i * 256 + tid;
      const int ub = i * 256 + ubase;
      const int r = idx >> 2, c = idx & 3;
      gload16((const char*)A + ((size_t)(mB + r) * 512 + kk + c * 8) * 2,
              (char*)&Asb[bufi][0] + ub * 16);
      gload16((const char*)Bw + ((size_t)(nB + r) * 512 + kk + c * 8) * 2,
              (char*)&Bsb[bufi][0] + ub * 16);
    }
  };

  f32x4 acc[4][4];
#pragma unroll
  for (int i = 0; i < 4; i++)
#pragma unroll
    for (int j = 0; j < 4; j++) acc[i][j] = f32x4{0.f, 0.f, 0.f, 0.f};

  stage(0, 0);
  __syncthreads();
  int buf = 0;

  for (int ks = 0; ks < 16; ++ks) {
    if (ks < 15) stage(buf ^ 1, (ks + 1) * 32);
    bf16x8 af[4], bfr[4];
#pragma unroll
    for (int t = 0; t < 4; t++) {
      af[t] = ld_bf8(&Asb[buf][(m0 + t * 16 + lr) * 32 + g * 8]);
      bfr[t] = ld_bf8(&Bsb[buf][(n0 + t * 16 + lr) * 32 + g * 8]);
    }
#pragma unroll
    for (int i = 0; i < 4; i++)
#pragma unroll
      for (int j = 0; j < 4; j++)
        acc[i][j] = mfma16(af[i], bfr[j], acc[i][j]);
    __syncthreads();
    buf ^= 1;
  }

  unsigned short* outz = outb + (size_t)z * SZX_E;  // Qp / Kp / Vt
#pragma unroll
  for (int j = 0; j < 4; j++) {
    const int n = nB + n0 + j * 16 + lr;
    const float bn = bias[n];
#pragma unroll
    for (int i = 0; i < 4; i++) {
#pragma unroll
      for (int r = 0; r < 4; r++) {
        const int m = mB + m0 + i * 16 + g * 4 + r;
        const float v = acc[i][j][r] + bn;
        if (z < 2) {
          outz[(size_t)m * 512 + n] = f2bf(v);
        } else {
          const int bb = m >> 11, s = m & 2047;
          const int hh = n >> 6, d = n & 63;
          outz[((size_t)((bb * 8 + hh) * 64 + d) << 11) + s] = f2bf(v);
        }
      }
    }
  }
}

// ---------------- output GEMM: fp32 out + bias + XCD swizzle ----------------
__global__ __launch_bounds__(256) void gemm_o(const unsigned short* __restrict__ A,
                                              const unsigned short* __restrict__ Bw,
                                              const float* __restrict__ bias,
                                              float* __restrict__ Cout) {
  __shared__ unsigned short Asb[2][4096];
  __shared__ unsigned short Bsb[2][4096];
  const int tid = threadIdx.x;
  const int l = tid & 63;
  const int w = tid >> 6;
  const int g = l >> 4;
  const int lr = l & 15;
  const int bid = blockIdx.x + (blockIdx.y << 2);
  const int lgg = (bid & 7) * 32 + (bid >> 3);
  const int nB = (lgg & 3) * 128;
  const int mB = (lgg >> 2) * 128;
  const int m0 = (w >> 1) * 64;
  const int n0 = (w & 1) * 64;
  const int ubase = tid & ~63;

  auto stage = [&](int bufi, int kk) {
#pragma unroll
    for (int i = 0; i < 2; i++) {
      const int idx = i * 256 + tid;
      const int ub = i * 256 + ubase;
      const int r = idx >> 2, c = idx & 3;
      gload16((const char*)A + ((size_t)(mB + r) * 512 + kk + c * 8) * 2,
              (char*)&Asb[bufi][0] + ub * 16);
      gload16((const char*)Bw + ((size_t)(nB + r) * 512 + kk + c * 8) * 2,
              (char*)&Bsb[bufi][0] + ub * 16);
    }
  };

  f32x4 acc[4][4];
#pragma unroll
  for (int i = 0; i < 4; i++)
#pragma unroll
    for (int j = 0; j < 4; j++) acc[i][j] = f32x4{0.f, 0.f, 0.f, 0.f};

  stage(0, 0);
  __syncthreads();
  int buf = 0;

  for (int ks = 0; ks < 16; ++ks) {
    if (ks < 15) stage(buf ^ 1, (ks + 1) * 32);
    bf16x8 af[4], bfr[4];
#pragma unroll
    for (int t = 0; t < 4; t++) {
      af[t] = ld_bf8(&Asb[buf][(m0 + t * 16 + lr) * 32 + g * 8]);
      bfr[t] = ld_bf8(&Bsb[buf][(n0 + t * 16 + lr) * 32 + g * 8]);
    }
#pragma unroll
    for (int i = 0; i < 4; i++)
#pragma unroll
      for (int j = 0; j < 4; j++)
        acc[i][j] = mfma16(af[i], bfr[j], acc[i][j]);
    __syncthreads();
    buf ^= 1;
  }

#pragma unroll
  for (int j = 0; j < 4; j++) {
    const int n = nB + n0 + j * 16 + lr;
    const float bn = bias[n];
#pragma unroll
    for (int i = 0; i < 4; i++) {
#pragma unroll
      for (int r = 0; r < 4; r++) {
        const int m = mB + m0 + i * 16 + g * 4 + r;
        Cout[(size_t)m * 512 + n] = acc[i][j][r] + bn;
      }
    }
  }
}

// ---------------- flash attention: 8-wave blocks, shared staging, counted vmcnt ----------------
// r21 math/layout; 256 blocks x 8 waves (512 thr). 8 waves share one staged K/V stream
// (halves per-CU staging traffic + gload issues); wave w owns q-rows qb*256 + w*32.
// Per wave 2 staging loads/tile -> VBAR2 steady state.
__global__ __launch_bounds__(512, 2) void attn_kernel(const unsigned short* __restrict__ Qp,
                                                      const unsigned short* __restrict__ Kp,
                                                      const unsigned short* __restrict__ Vt,
                                                      const float* __restrict__ rel_emb,
                                                      unsigned short* __restrict__ At) {
  __shared__ float bias_s[257];
  __shared__ unsigned short K_lds[3][4096];  // [64 kv][64 d], chunk-swizzled
  __shared__ unsigned short V_lds[3][4096];  // [64 d][64 s], chunk-swizzled
  const int bid0 = blockIdx.x;
  const int lg = (bid0 & 7) * 32 + (bid0 >> 3);  // XCD-bijective remap (256 % 8 == 0)
  const int qb = lg & 7;
  const int h = (lg >> 3) & 7;
  const int b = lg >> 6;
  const int tid = threadIdx.x;
  const int lane = tid & 63, w = tid >> 6;  // w in 0..7
  const int hi = lane >> 5, q31 = lane & 31;
  const int q0w = qb * 256 + w * 32;
  const int tq = q0w + q31;
  const float SCL = 0.125f * 1.44269504f;

  const char* kstage = (const char*)Kp + ((size_t)b * 2048 * 512 + h * 64) * 2;
  const char* vstage = (const char*)Vt + ((size_t)(b * 8 + h) * 64 * 2048) * 2;

  // wave w stages K slot w and V slot w (1024 B each; 8 rows per slot)
  const int rr = w * 8 + (lane >> 3);         // row 0..63
  const int ch = (lane & 7) ^ (rr & 7);       // inverse-swizzled 16B chunk
  const char* gpK = kstage + (size_t)rr * 1024 + ch * 16;
  const char* gpV = vstage + (size_t)rr * 4096 + ch * 16;
  const int dslot = w * 1024;

  auto STAGE = [&](int bufi) {
    gload16(gpK, (char*)&K_lds[bufi][0] + dslot);
    gload16(gpV, (char*)&V_lds[bufi][0] + dslot);
    gpK += (size_t)64 * 1024;  // next 64-kv tile of K rows
    gpV += 128;                // next 64 s-columns of V
  };

  // Q loads first (FIFO head; drained by the prologue __syncthreads)
  const unsigned short* qptr = Qp + (size_t)(b * 2048 + tq) * 512 + h * 64 + hi * 8;
  const bf16x8 qf0 = ld_bf8(qptr);
  const bf16x8 qf1 = ld_bf8(qptr + 16);
  const bf16x8 qf2 = ld_bf8(qptr + 32);
  const bf16x8 qf3 = ld_bf8(qptr + 48);

  STAGE(0);  // tile 0
  STAGE(1);  // tile 1
  for (int i = tid; i < 257; i += 512) bias_s[i] = rel_emb[i * 8 + h] * 1.44269504f;
  if (tid == 511) bias_s[256] = rel_emb[256 * 8 + h] * 1.44269504f;
  __syncthreads();  // one-time full drain (bias + prologue stages + Q)
  const float bias_lo = bias_s[0], bias_hi = bias_s[256];

  const int rswz = q31 & 7;
  int koff[4], voff[4];
#pragma unroll
  for (int c = 0; c < 4; c++) koff[c] = q31 * 64 + (((2 * c + hi) ^ rswz) << 3);
#pragma unroll
  for (int ks = 0; ks < 4; ks++) voff[ks] = q31 * 64 + (((ks * 2 + hi) ^ rswz) << 3);

  const f32x16 z16 = {0.f, 0.f, 0.f, 0.f, 0.f, 0.f, 0.f, 0.f,
                      0.f, 0.f, 0.f, 0.f, 0.f, 0.f, 0.f, 0.f};
  f32x16 o_lo = z16, o_hi = z16;
  float l_run = 0.f;

  auto TILE = [&](const unsigned short* kb, const unsigned short* vb, int s0) {
    bf16x8 kfl0 = ld_bf8(kb + koff[0]);
    bf16x8 kfh0 = ld_bf8(kb + 2048 + koff[0]);
    bf16x8 kfl1 = ld_bf8(kb + koff[1]);
    bf16x8 kfh1 = ld_bf8(kb + 2048 + koff[1]);
    bf16x8 kfl2 = ld_bf8(kb + koff[2]);
    bf16x8 kfh2 = ld_bf8(kb + 2048 + koff[2]);
    bf16x8 kfl3 = ld_bf8(kb + koff[3]);
    bf16x8 kfh3 = ld_bf8(kb + 2048 + koff[3]);
    bf16x8 vl[4], vh[4];
#pragma unroll
    for (int ks = 0; ks < 4; ks++) {
      vl[ks] = ld_bf8(vb + voff[ks]);
      vh[ks] = ld_bf8(vb + 2048 + voff[ks]);
    }

    f32x16 sa, sb;
    sa = mfma32(kfl0, qf0, z16);
    sb = mfma32(kfh0, qf0, z16);
    sa = mfma32(kfl1, qf1, sa);
    sb = mfma32(kfh1, qf1, sb);
    sa = mfma32(kfl2, qf2, sa);
    sb = mfma32(kfh2, qf2, sb);
    sa = mfma32(kfl3, qf3, sa);
    sb = mfma32(kfh3, qf3, sb);

    const int relmin = q0w - s0 - 63;
    const int relmax = q0w + 31 - s0;
    float SCL2, off0;
    if (relmin >= 128 || relmax <= -128) {
      SCL2 = SCL;
      off0 = (relmin >= 128) ? bias_hi : bias_lo;
    } else {
#pragma unroll
      for (int r = 0; r < 16; r++) {
        const int rowA = (r & 3) + 8 * (r >> 2) + 4 * hi;
        const int rA = tq - s0 - rowA;
        const int rB = rA - 32;
        const int iA = (rA < -128 ? -128 : (rA > 128 ? 128 : rA)) + 128;
        const int iB = (rB < -128 ? -128 : (rB > 128 ? 128 : rB)) + 128;
        sa[r] = fmaf(sa[r], SCL, bias_s[iA]);
        sb[r] = fmaf(sb[r], SCL, bias_s[iB]);
      }
      SCL2 = 1.f;
      off0 = 0.f;
    }

#pragma unroll
    for (int r = 0; r < 16; r++) {
      sa[r] = exp2_fast(fmaf(sa[r], SCL2, off0));
      sb[r] = exp2_fast(fmaf(sb[r], SCL2, off0));
    }
    float s8[8];
#pragma unroll
    for (int i = 0; i < 8; i++)
      s8[i] = (sa[i] + sa[i + 8]) + (sb[i] + sb[i + 8]);
    float ps = ((s8[0] + s8[1]) + (s8[2] + s8[3])) + ((s8[4] + s8[5]) + (s8[6] + s8[7]));
    ps += __shfl_xor(ps, 32, 64);
    l_run += ps;

    bf16x8 pa[4];
#pragma unroll
    for (int ks = 0; ks < 4; ks++) {
      const int c8 = (ks & 1) * 8;
      const f32x16& src = (ks < 2) ? sa : sb;
      unsigned int a0 = cvt_pk_bf16(src[c8 + 0], src[c8 + 1]);
      unsigned int b0 = cvt_pk_bf16(src[c8 + 4], src[c8 + 5]);
      unsigned int a1 = cvt_pk_bf16(src[c8 + 2], src[c8 + 3]);
      unsigned int b1 = cvt_pk_bf16(src[c8 + 6], src[c8 + 7]);
      plane32_swap(a0, b0);
      plane32_swap(a1, b1);
      pa[ks] = __builtin_bit_cast(bf16x8, u32x4{a0, a1, b0, b1});
    }

#pragma unroll
    for (int ks = 0; ks < 4; ks++) {
      o_lo = mfma32(pa[ks], vl[ks], o_lo);
      o_hi = mfma32(pa[ks], vh[ks], o_hi);
    }
  };

  const unsigned short* K0 = &K_lds[0][0];
  const unsigned short* K1 = &K_lds[1][0];
  const unsigned short* K2 = &K_lds[2][0];
  const unsigned short* V0 = &V_lds[0][0];
  const unsigned short* V1 = &V_lds[1][0];
  const unsigned short* V2 = &V_lds[2][0];

  // tiles 0..29: tile u (buffer u%3) computes after staging tile u+2 into buffer (u+2)%3.
  for (int it = 0; it < 10; ++it) {
    const int u = it * 3;
    VBAR2; STAGE(2); TILE(K0, V0, u * 64);
    VBAR2; STAGE(0); TILE(K1, V1, (u + 1) * 64);
    VBAR2; STAGE(1); TILE(K2, V2, (u + 2) * 64);
  }
  // tiles 30 (buf 0), 31 (buf 1): no more staging; final tile needs full drain.
  VBAR2; TILE(K0, V0, 30 * 64);
  VBAR0; TILE(K1, V1, 31 * 64);

  const float inv = 1.f / l_run;
#pragma unroll
  for (int r2 = 0; r2 < 16; r2++) {
    const int ro = (r2 & 3) + 8 * (r2 >> 2) + 4 * hi;
    const float rr2 = __shfl(inv, ro, 64);
    unsigned short* op = At + (size_t)(b * 2048 + q0w + ro) * 512 + h * 64;
    op[q31] = f2bf(o_lo[r2] * rr2);
    op[32 + q31] = f2bf(o_hi[r2] * rr2);
  }
}

// ---------------- host ----------------
extern "C" void kernel_launch(void* const* d_in, const int* in_sizes, int n_in,
                              void* d_out, int out_size, void* d_ws, size_t ws_size,
                              hipStream_t stream) {
  const float* query = (const float*)d_in[0];
  const float* key   = (const float*)d_in[1];
  const float* value = (const float*)d_in[2];
  const float* Wq = (const float*)d_in[3];
  const float* bq = (const float*)d_in[4];
  const float* Wk = (const float*)d_in[5];
  const float* bk = (const float*)d_in[6];
  const float* Wv = (const float*)d_in[7];
  const float* bv = (const float*)d_in[8];
  const float* Wo = (const float*)d_in[9];
  const float* bo = (const float*)d_in[10];
  const float* rel = (const float*)d_in[11];

  char* ws = (char*)d_ws;
  unsigned short* base = (unsigned short*)ws;       // xq xk xv | wq wk wv wo | ...
  unsigned short* wo = base + 3 * SZX_E + 3 * SZW_E;
  unsigned short* Qp = base + 3 * SZX_E + 4 * SZW_E;
  unsigned short* Kp = Qp + SZX_E;
  unsigned short* Vt = Kp + SZX_E;
  unsigned short* At = Vt + SZX_E;

  cvt_all<<<dim3(13312), dim3(256), 0, stream>>>(query, key, value, Wq, Wk, Wv, Wo, base);

  dim3 blk(256);
  gemm_qkv<<<dim3(4, 64, 3), blk, 0, stream>>>(base, bq, bk, bv, Qp);

  attn_kernel<<<dim3(256), dim3(512), 0, stream>>>(Qp, Kp, Vt, rel, At);

  gemm_o<<<dim3(4, 64), blk, 0, stream>>>(At, wo, bo, (float*)d_out);
}

// Round 23
// 102.037 us; speedup vs baseline: 1.0192x; 1.0192x over previous
//
#include <hip/hip_runtime.h>

typedef __attribute__((ext_vector_type(4))) float f32x4;
typedef __attribute__((ext_vector_type(16))) float f32x16;
typedef __attribute__((ext_vector_type(4))) unsigned short u16x4;
typedef __attribute__((ext_vector_type(8))) unsigned short u16x8;
typedef __attribute__((ext_vector_type(4))) unsigned int u32x4;
typedef __attribute__((ext_vector_type(8))) __bf16 bf16x8;

#define SZX_E ((size_t)4 * 2048 * 512)  // elements per activation tensor
#define SZW_E ((size_t)512 * 512)

__device__ __forceinline__ unsigned short f2bf(float f) {
  unsigned int u = __builtin_bit_cast(unsigned int, f);
  u += 0x7fffu + ((u >> 16) & 1u);
  return (unsigned short)(u >> 16);
}

__device__ __forceinline__ bf16x8 ld_bf8(const unsigned short* p) {
  return __builtin_bit_cast(bf16x8, *(const u16x8*)p);
}

__device__ __forceinline__ f32x4 mfma16(bf16x8 a, bf16x8 b, f32x4 c) {
  return __builtin_amdgcn_mfma_f32_16x16x32_bf16(a, b, c, 0, 0, 0);
}

__device__ __forceinline__ f32x16 mfma32(bf16x8 a, bf16x8 b, f32x16 c) {
  return __builtin_amdgcn_mfma_f32_32x32x16_bf16(a, b, c, 0, 0, 0);
}

__device__ __forceinline__ unsigned int cvt_pk_bf16(float lo, float hi) {
  unsigned int r;
  asm("v_cvt_pk_bf16_f32 %0, %1, %2" : "=v"(r) : "v"(lo), "v"(hi));
  return r;
}

__device__ __forceinline__ void plane32_swap(unsigned int& a, unsigned int& b) {
  asm("v_permlane32_swap_b32 %0, %1" : "+v"(a), "+v"(b));
}

// raw v_exp_f32 (2^x); args bounded (|scores*log2e| < ~10) -> equals exp2f.
__device__ __forceinline__ float exp2_fast(float x) {
  float r;
  asm("v_exp_f32 %0, %1" : "=v"(r) : "v"(x));
  return r;
}

// async global->LDS, 16B per lane; LDS dest = WAVE-UNIFORM base, HW adds lane*16
__device__ __forceinline__ void gload16(const void* g, void* l) {
  __builtin_amdgcn_global_load_lds(
      (const __attribute__((address_space(1))) unsigned int*)g,
      (__attribute__((address_space(3))) unsigned int*)l, 16, 0, 0);
}

// counted-vmcnt barrier (T4): my own previous-tile staging loads done, then block barrier.
// sched_barrier fences prevent hoisting (rule #18).
#define VBAR4 do { \
    asm volatile("s_waitcnt vmcnt(4)" ::: "memory"); \
    __builtin_amdgcn_sched_barrier(0); \
    __builtin_amdgcn_s_barrier(); \
    __builtin_amdgcn_sched_barrier(0); \
  } while (0)
#define VBAR0 do { \
    asm volatile("s_waitcnt vmcnt(0)" ::: "memory"); \
    __builtin_amdgcn_sched_barrier(0); \
    __builtin_amdgcn_s_barrier(); \
    __builtin_amdgcn_sched_barrier(0); \
  } while (0)

// ---------------- fused fp32 -> bf16 convert (all 7 tensors, one launch) ----------------
__global__ __launch_bounds__(256) void cvt_all(const float* __restrict__ q_,
                                               const float* __restrict__ k_,
                                               const float* __restrict__ v_,
                                               const float* __restrict__ wq_,
                                               const float* __restrict__ wk_,
                                               const float* __restrict__ wv_,
                                               const float* __restrict__ wo_,
                                               unsigned short* __restrict__ out) {
  const int bq = blockIdx.x;
  const float* src;
  size_t segbase, li;
  if (bq < 12288) {
    const int s = bq >> 12;
    src = (s == 0) ? q_ : (s == 1) ? k_ : v_;
    li = (size_t)(bq & 4095) * 256 + threadIdx.x;
    segbase = (size_t)s * 4194304;
  } else {
    const int s = (bq - 12288) >> 8;
    src = (s == 0) ? wq_ : (s == 1) ? wk_ : (s == 2) ? wv_ : wo_;
    li = (size_t)((bq - 12288) & 255) * 256 + threadIdx.x;
    segbase = 12582912 + (size_t)s * 262144;
  }
  const f32x4 v = *(const f32x4*)(src + li * 4);
  u16x4 r;
  r[0] = f2bf(v[0]); r[1] = f2bf(v[1]); r[2] = f2bf(v[2]); r[3] = f2bf(v[3]);
  *(u16x4*)(out + segbase + li * 4) = r;
}

// ---------------- fused QKV GEMM: z = 0/1/2 -> Q/K/V projection + XCD swizzle ----------------
__global__ __launch_bounds__(256) void gemm_qkv(const unsigned short* __restrict__ base,
                                                const float* __restrict__ bq,
                                                const float* __restrict__ bk,
                                                const float* __restrict__ bv,
                                                unsigned short* __restrict__ outb) {
  __shared__ unsigned short Asb[2][4096];
  __shared__ unsigned short Bsb[2][4096];
  const int z = blockIdx.z;
  const unsigned short* A = base + (size_t)z * SZX_E;
  const unsigned short* Bw = base + 3 * SZX_E + (size_t)z * SZW_E;
  const float* bias = (z == 0) ? bq : (z == 1) ? bk : bv;

  const int tid = threadIdx.x;
  const int l = tid & 63;
  const int w = tid >> 6;
  const int g = l >> 4;
  const int lr = l & 15;
  const int bid = blockIdx.x + (blockIdx.y << 2);
  const int lgg = (bid & 7) * 32 + (bid >> 3);
  const int nB = (lgg & 3) * 128;
  const int mB = (lgg >> 2) * 128;
  const int m0 = (w >> 1) * 64;
  const int n0 = (w & 1) * 64;
  const int ubase = tid & ~63;

  auto stage = [&](int bufi, int kk) {
#pragma unroll
    for (int i = 0; i < 2; i++) {
      const int idx = i * 256 + tid;
      const int ub = i * 256 + ubase;
      const int r = idx >> 2, c = idx & 3;
      gload16((const char*)A + ((size_t)(mB + r) * 512 + kk + c * 8) * 2,
              (char*)&Asb[bufi][0] + ub * 16);
      gload16((const char*)Bw + ((size_t)(nB + r) * 512 + kk + c * 8) * 2,
              (char*)&Bsb[bufi][0] + ub * 16);
    }
  };

  f32x4 acc[4][4];
#pragma unroll
  for (int i = 0; i < 4; i++)
#pragma unroll
    for (int j = 0; j < 4; j++) acc[i][j] = f32x4{0.f, 0.f, 0.f, 0.f};

  stage(0, 0);
  __syncthreads();
  int buf = 0;

  for (int ks = 0; ks < 16; ++ks) {
    if (ks < 15) stage(buf ^ 1, (ks + 1) * 32);
    bf16x8 af[4], bfr[4];
#pragma unroll
    for (int t = 0; t < 4; t++) {
      af[t] = ld_bf8(&Asb[buf][(m0 + t * 16 + lr) * 32 + g * 8]);
      bfr[t] = ld_bf8(&Bsb[buf][(n0 + t * 16 + lr) * 32 + g * 8]);
    }
#pragma unroll
    for (int i = 0; i < 4; i++)
#pragma unroll
      for (int j = 0; j < 4; j++)
        acc[i][j] = mfma16(af[i], bfr[j], acc[i][j]);
    __syncthreads();
    buf ^= 1;
  }

  unsigned short* outz = outb + (size_t)z * SZX_E;  // Qp / Kp / Vt
#pragma unroll
  for (int j = 0; j < 4; j++) {
    const int n = nB + n0 + j * 16 + lr;
    const float bn = bias[n];
#pragma unroll
    for (int i = 0; i < 4; i++) {
#pragma unroll
      for (int r = 0; r < 4; r++) {
        const int m = mB + m0 + i * 16 + g * 4 + r;
        const float v = acc[i][j][r] + bn;
        if (z < 2) {
          outz[(size_t)m * 512 + n] = f2bf(v);
        } else {
          const int bb = m >> 11, s = m & 2047;
          const int hh = n >> 6, d = n & 63;
          outz[((size_t)((bb * 8 + hh) * 64 + d) << 11) + s] = f2bf(v);
        }
      }
    }
  }
}

// ---------------- output GEMM: fp32 out + bias + XCD swizzle ----------------
__global__ __launch_bounds__(256) void gemm_o(const unsigned short* __restrict__ A,
                                              const unsigned short* __restrict__ Bw,
                                              const float* __restrict__ bias,
                                              float* __restrict__ Cout) {
  __shared__ unsigned short Asb[2][4096];
  __shared__ unsigned short Bsb[2][4096];
  const int tid = threadIdx.x;
  const int l = tid & 63;
  const int w = tid >> 6;
  const int g = l >> 4;
  const int lr = l & 15;
  const int bid = blockIdx.x + (blockIdx.y << 2);
  const int lgg = (bid & 7) * 32 + (bid >> 3);
  const int nB = (lgg & 3) * 128;
  const int mB = (lgg >> 2) * 128;
  const int m0 = (w >> 1) * 64;
  const int n0 = (w & 1) * 64;
  const int ubase = tid & ~63;

  auto stage = [&](int bufi, int kk) {
#pragma unroll
    for (int i = 0; i < 2; i++) {
      const int idx = i * 256 + tid;
      const int ub = i * 256 + ubase;
      const int r = idx >> 2, c = idx & 3;
      gload16((const char*)A + ((size_t)(mB + r) * 512 + kk + c * 8) * 2,
              (char*)&Asb[bufi][0] + ub * 16);
      gload16((const char*)Bw + ((size_t)(nB + r) * 512 + kk + c * 8) * 2,
              (char*)&Bsb[bufi][0] + ub * 16);
    }
  };

  f32x4 acc[4][4];
#pragma unroll
  for (int i = 0; i < 4; i++)
#pragma unroll
    for (int j = 0; j < 4; j++) acc[i][j] = f32x4{0.f, 0.f, 0.f, 0.f};

  stage(0, 0);
  __syncthreads();
  int buf = 0;

  for (int ks = 0; ks < 16; ++ks) {
    if (ks < 15) stage(buf ^ 1, (ks + 1) * 32);
    bf16x8 af[4], bfr[4];
#pragma unroll
    for (int t = 0; t < 4; t++) {
      af[t] = ld_bf8(&Asb[buf][(m0 + t * 16 + lr) * 32 + g * 8]);
      bfr[t] = ld_bf8(&Bsb[buf][(n0 + t * 16 + lr) * 32 + g * 8]);
    }
#pragma unroll
    for (int i = 0; i < 4; i++)
#pragma unroll
      for (int j = 0; j < 4; j++)
        acc[i][j] = mfma16(af[i], bfr[j], acc[i][j]);
    __syncthreads();
    buf ^= 1;
  }

#pragma unroll
  for (int j = 0; j < 4; j++) {
    const int n = nB + n0 + j * 16 + lr;
    const float bn = bias[n];
#pragma unroll
    for (int i = 0; i < 4; i++) {
#pragma unroll
      for (int r = 0; r < 4; r++) {
        const int m = mB + m0 + i * 16 + g * 4 + r;
        Cout[(size_t)m * 512 + n] = acc[i][j][r] + bn;
      }
    }
  }
}

// ---------------- flash attention: triple-buffer + counted vmcnt (T4) ----------------
// r20 math/layout; per-tile __syncthreads (vmcnt(0) drain) replaced by
// s_waitcnt vmcnt(4) + raw s_barrier over 3 LDS buffers -> staging loads span barriers.
__global__ __launch_bounds__(256, 2) void attn_kernel(const unsigned short* __restrict__ Qp,
                                                      const unsigned short* __restrict__ Kp,
                                                      const unsigned short* __restrict__ Vt,
                                                      const float* __restrict__ rel_emb,
                                                      unsigned short* __restrict__ At) {
  __shared__ float bias_s[257];
  __shared__ unsigned short K_lds[3][4096];  // [64 kv][64 d], chunk-swizzled
  __shared__ unsigned short V_lds[3][4096];  // [64 d][64 s], chunk-swizzled
  const int bid0 = blockIdx.x;
  const int lg = (bid0 & 7) * 64 + (bid0 >> 3);  // XCD-bijective remap (512 % 8 == 0)
  const int qb = lg & 15;
  const int h = (lg >> 4) & 7;
  const int b = lg >> 7;
  const int tid = threadIdx.x;
  const int lane = tid & 63, w = tid >> 6;
  const int hi = lane >> 5, q31 = lane & 31;
  const int q0w = qb * 128 + w * 32;
  const int tq = q0w + q31;
  const float SCL = 0.125f * 1.44269504f;

  const bool isK = (w < 2);
  const char* sbase = isK ? (const char*)Kp + ((size_t)b * 2048 * 512 + h * 64) * 2
                          : (const char*)Vt + ((size_t)(b * 8 + h) * 64 * 2048) * 2;
  const size_t step = isK ? (size_t)64 * 1024 : 128;
  const int i0 = (w & 1) * 4;
  const int rr0 = (i0 + 0) * 8 + (lane >> 3), ch0 = (lane & 7) ^ (rr0 & 7);
  const int rr1 = (i0 + 1) * 8 + (lane >> 3), ch1 = (lane & 7) ^ (rr1 & 7);
  const int rr2 = (i0 + 2) * 8 + (lane >> 3), ch2 = (lane & 7) ^ (rr2 & 7);
  const int rr3 = (i0 + 3) * 8 + (lane >> 3), ch3 = (lane & 7) ^ (rr3 & 7);
  const size_t rstr = isK ? 1024 : 4096;
  const char* gp0 = sbase + (size_t)rr0 * rstr + ch0 * 16;
  const char* gp1 = sbase + (size_t)rr1 * rstr + ch1 * 16;
  const char* gp2 = sbase + (size_t)rr2 * rstr + ch2 * 16;
  const char* gp3 = sbase + (size_t)rr3 * rstr + ch3 * 16;
  char* dbA = (isK ? (char*)&K_lds[0][0] : (char*)&V_lds[0][0]) + i0 * 1024;
  char* dbB = (isK ? (char*)&K_lds[1][0] : (char*)&V_lds[1][0]) + i0 * 1024;
  char* dbC = (isK ? (char*)&K_lds[2][0] : (char*)&V_lds[2][0]) + i0 * 1024;

  auto STAGE = [&](char* dbase) {
    gload16(gp0, dbase);
    gload16(gp1, dbase + 1024);
    gload16(gp2, dbase + 2048);
    gload16(gp3, dbase + 3072);
    gp0 += step; gp1 += step; gp2 += step; gp3 += step;
  };

  // Q loads first (FIFO head; drained by the prologue __syncthreads)
  const unsigned short* qptr = Qp + (size_t)(b * 2048 + tq) * 512 + h * 64 + hi * 8;
  const bf16x8 qf0 = ld_bf8(qptr);
  const bf16x8 qf1 = ld_bf8(qptr + 16);
  const bf16x8 qf2 = ld_bf8(qptr + 32);
  const bf16x8 qf3 = ld_bf8(qptr + 48);

  STAGE(dbA);  // tile 0
  STAGE(dbB);  // tile 1
  for (int i = tid; i < 257; i += 256) bias_s[i] = rel_emb[i * 8 + h] * 1.44269504f;
  __syncthreads();  // one-time full drain (bias + prologue stages + Q)
  const float bias_lo = bias_s[0], bias_hi = bias_s[256];

  const int rswz = q31 & 7;
  int koff[4], voff[4];
#pragma unroll
  for (int c = 0; c < 4; c++) koff[c] = q31 * 64 + (((2 * c + hi) ^ rswz) << 3);
#pragma unroll
  for (int ks = 0; ks < 4; ks++) voff[ks] = q31 * 64 + (((ks * 2 + hi) ^ rswz) << 3);

  const f32x16 z16 = {0.f, 0.f, 0.f, 0.f, 0.f, 0.f, 0.f, 0.f,
                      0.f, 0.f, 0.f, 0.f, 0.f, 0.f, 0.f, 0.f};
  f32x16 o_lo = z16, o_hi = z16;
  float l_run = 0.f;

  auto TILE = [&](const unsigned short* kb, const unsigned short* vb, int s0) {
    bf16x8 kfl0 = ld_bf8(kb + koff[0]);
    bf16x8 kfh0 = ld_bf8(kb + 2048 + koff[0]);
    bf16x8 kfl1 = ld_bf8(kb + koff[1]);
    bf16x8 kfh1 = ld_bf8(kb + 2048 + koff[1]);
    bf16x8 kfl2 = ld_bf8(kb + koff[2]);
    bf16x8 kfh2 = ld_bf8(kb + 2048 + koff[2]);
    bf16x8 kfl3 = ld_bf8(kb + koff[3]);
    bf16x8 kfh3 = ld_bf8(kb + 2048 + koff[3]);
    bf16x8 vl[4], vh[4];
#pragma unroll
    for (int ks = 0; ks < 4; ks++) {
      vl[ks] = ld_bf8(vb + voff[ks]);
      vh[ks] = ld_bf8(vb + 2048 + voff[ks]);
    }

    f32x16 sa, sb;
    sa = mfma32(kfl0, qf0, z16);
    sb = mfma32(kfh0, qf0, z16);
    sa = mfma32(kfl1, qf1, sa);
    sb = mfma32(kfh1, qf1, sb);
    sa = mfma32(kfl2, qf2, sa);
    sb = mfma32(kfh2, qf2, sb);
    sa = mfma32(kfl3, qf3, sa);
    sb = mfma32(kfh3, qf3, sb);

    const int relmin = q0w - s0 - 63;
    const int relmax = q0w + 31 - s0;
    float SCL2, off0;
    if (relmin >= 128 || relmax <= -128) {
      SCL2 = SCL;
      off0 = (relmin >= 128) ? bias_hi : bias_lo;
    } else {
#pragma unroll
      for (int r = 0; r < 16; r++) {
        const int rowA = (r & 3) + 8 * (r >> 2) + 4 * hi;
        const int rA = tq - s0 - rowA;
        const int rB = rA - 32;
        const int iA = (rA < -128 ? -128 : (rA > 128 ? 128 : rA)) + 128;
        const int iB = (rB < -128 ? -128 : (rB > 128 ? 128 : rB)) + 128;
        sa[r] = fmaf(sa[r], SCL, bias_s[iA]);
        sb[r] = fmaf(sb[r], SCL, bias_s[iB]);
      }
      SCL2 = 1.f;
      off0 = 0.f;
    }

#pragma unroll
    for (int r = 0; r < 16; r++) {
      sa[r] = exp2_fast(fmaf(sa[r], SCL2, off0));
      sb[r] = exp2_fast(fmaf(sb[r], SCL2, off0));
    }
    float s8[8];
#pragma unroll
    for (int i = 0; i < 8; i++)
      s8[i] = (sa[i] + sa[i + 8]) + (sb[i] + sb[i + 8]);
    float ps = ((s8[0] + s8[1]) + (s8[2] + s8[3])) + ((s8[4] + s8[5]) + (s8[6] + s8[7]));
    ps += __shfl_xor(ps, 32, 64);
    l_run += ps;

    bf16x8 pa[4];
#pragma unroll
    for (int ks = 0; ks < 4; ks++) {
      const int c8 = (ks & 1) * 8;
      const f32x16& src = (ks < 2) ? sa : sb;
      unsigned int a0 = cvt_pk_bf16(src[c8 + 0], src[c8 + 1]);
      unsigned int b0 = cvt_pk_bf16(src[c8 + 4], src[c8 + 5]);
      unsigned int a1 = cvt_pk_bf16(src[c8 + 2], src[c8 + 3]);
      unsigned int b1 = cvt_pk_bf16(src[c8 + 6], src[c8 + 7]);
      plane32_swap(a0, b0);
      plane32_swap(a1, b1);
      pa[ks] = __builtin_bit_cast(bf16x8, u32x4{a0, a1, b0, b1});
    }

#pragma unroll
    for (int ks = 0; ks < 4; ks++) {
      o_lo = mfma32(pa[ks], vl[ks], o_lo);
      o_hi = mfma32(pa[ks], vh[ks], o_hi);
    }
  };

  const unsigned short* K0 = &K_lds[0][0];
  const unsigned short* K1 = &K_lds[1][0];
  const unsigned short* K2 = &K_lds[2][0];
  const unsigned short* V0 = &V_lds[0][0];
  const unsigned short* V1 = &V_lds[1][0];
  const unsigned short* V2 = &V_lds[2][0];

  // tiles 0..29: tile u (buffer u%3) computes after staging tile u+2 into buffer (u+2)%3.
  for (int it = 0; it < 10; ++it) {
    const int u = it * 3;
    VBAR4; STAGE(dbC); TILE(K0, V0, u * 64);
    VBAR4; STAGE(dbA); TILE(K1, V1, (u + 1) * 64);
    VBAR4; STAGE(dbB); TILE(K2, V2, (u + 2) * 64);
  }
  // tiles 30 (buf 0), 31 (buf 1): no more staging; final tile needs full drain.
  VBAR4; TILE(K0, V0, 30 * 64);
  VBAR0; TILE(K1, V1, 31 * 64);

  const float inv = 1.f / l_run;
#pragma unroll
  for (int r2 = 0; r2 < 16; r2++) {
    const int ro = (r2 & 3) + 8 * (r2 >> 2) + 4 * hi;
    const float rr = __shfl(inv, ro, 64);
    unsigned short* op = At + (size_t)(b * 2048 + q0w + ro) * 512 + h * 64;
    op[q31] = f2bf(o_lo[r2] * rr);
    op[32 + q31] = f2bf(o_hi[r2] * rr);
  }
}

// ---------------- host ----------------
extern "C" void kernel_launch(void* const* d_in, const int* in_sizes, int n_in,
                              void* d_out, int out_size, void* d_ws, size_t ws_size,
                              hipStream_t stream) {
  const float* query = (const float*)d_in[0];
  const float* key   = (const float*)d_in[1];
  const float* value = (const float*)d_in[2];
  const float* Wq = (const float*)d_in[3];
  const float* bq = (const float*)d_in[4];
  const float* Wk = (const float*)d_in[5];
  const float* bk = (const float*)d_in[6];
  const float* Wv = (const float*)d_in[7];
  const float* bv = (const float*)d_in[8];
  const float* Wo = (const float*)d_in[9];
  const float* bo = (const float*)d_in[10];
  const float* rel = (const float*)d_in[11];

  char* ws = (char*)d_ws;
  unsigned short* base = (unsigned short*)ws;       // xq xk xv | wq wk wv wo | ...
  unsigned short* wo = base + 3 * SZX_E + 3 * SZW_E;
  unsigned short* Qp = base + 3 * SZX_E + 4 * SZW_E;
  unsigned short* Kp = Qp + SZX_E;
  unsigned short* Vt = Kp + SZX_E;
  unsigned short* At = Vt + SZX_E;

  cvt_all<<<dim3(13312), dim3(256), 0, stream>>>(query, key, value, Wq, Wk, Wv, Wo, base);

  dim3 blk(256);
  gemm_qkv<<<dim3(4, 64, 3), blk, 0, stream>>>(base, bq, bk, bv, Qp);

  attn_kernel<<<dim3(512), blk, 0, stream>>>(Qp, Kp, Vt, rel, At);

  gemm_o<<<dim3(4, 64), blk, 0, stream>>>(At, wo, bo, (float*)d_out);
}